// Round 4
// baseline (694.280 us; speedup 1.0000x reference)
//
#include <hip/hip_runtime.h>
#include <hip/hip_bf16.h>
#include <math.h>

#define NN 50000
#define NE 800000
#define HD 128
#define SCAN_BLOCKS ((NN + 255) / 256)   // 196

// ---------------- degree computation ----------------
__global__ __launch_bounds__(256) void deg_kernel(const int* __restrict__ src,
                                                  const int* __restrict__ dst,
                                                  float* __restrict__ in_deg,
                                                  float* __restrict__ out_deg) {
    int e = blockIdx.x * 256 + threadIdx.x;
    if (e < NE) {
        atomicAdd(&in_deg[dst[e]], 1.0f);
        atomicAdd(&out_deg[src[e]], 1.0f);
    }
}

// ---------------- node init: norms + h0 pre-scaled by norm_s ----------------
__global__ __launch_bounds__(256) void node_init_kernel(const float* __restrict__ cx,
                                                        const float* __restrict__ cy,
                                                        const float* __restrict__ in_deg,
                                                        const float* __restrict__ out_deg,
                                                        float* __restrict__ norm_s,
                                                        float* __restrict__ norm_d,
                                                        float* __restrict__ h0s) {
    int i = blockIdx.x * 256 + threadIdx.x;
    if (i < NN) {
        float id = in_deg[i], od = out_deg[i];
        float ns = 1.0f / sqrtf(fmaxf(od, 1.0f));
        norm_s[i] = ns;
        norm_d[i] = 1.0f / sqrtf(fmaxf(id, 1.0f));
        h0s[i * 3 + 0] = id * ns;
        h0s[i * 3 + 1] = cx[i] * ns;
        h0s[i * 3 + 2] = cy[i] * ns;
    }
}

// ---------------- 3-pass parallel exclusive scan of in-degree counts ----------------
__global__ __launch_bounds__(256) void blocksum_kernel(const float* __restrict__ counts,
                                                       int* __restrict__ block_sums) {
    __shared__ int red[256];
    int t = threadIdx.x;
    int i = blockIdx.x * 256 + t;
    red[t] = (i < NN) ? (int)counts[i] : 0;
    __syncthreads();
    #pragma unroll
    for (int off = 128; off > 0; off >>= 1) {
        if (t < off) red[t] += red[t + off];
        __syncthreads();
    }
    if (t == 0) block_sums[blockIdx.x] = red[0];
}

__global__ __launch_bounds__(256) void scan_sums_kernel(int* __restrict__ block_sums) {
    __shared__ int buf[256];
    int t = threadIdx.x;
    int v = (t < SCAN_BLOCKS) ? block_sums[t] : 0;
    buf[t] = v;
    __syncthreads();
    #pragma unroll
    for (int off = 1; off < 256; off <<= 1) {
        int add = (t >= off) ? buf[t - off] : 0;
        __syncthreads();
        buf[t] += add;
        __syncthreads();
    }
    if (t < SCAN_BLOCKS) block_sums[t] = buf[t] - v;   // exclusive
}

__global__ __launch_bounds__(256) void rowptr_kernel(const float* __restrict__ counts,
                                                     const int* __restrict__ block_sums,
                                                     int* __restrict__ row_ptr) {
    __shared__ int buf[256];
    int t = threadIdx.x;
    int i = blockIdx.x * 256 + t;
    int v = (i < NN) ? (int)counts[i] : 0;
    buf[t] = v;
    __syncthreads();
    #pragma unroll
    for (int off = 1; off < 256; off <<= 1) {
        int add = (t >= off) ? buf[t - off] : 0;
        __syncthreads();
        buf[t] += add;
        __syncthreads();
    }
    if (i < NN) row_ptr[i] = block_sums[blockIdx.x] + buf[t] - v;
    if (i == 0) row_ptr[NN] = NE;   // total edge count is a constant
}

// ---------------- CSR build: bucket scatter of src ids ----------------
__global__ __launch_bounds__(256) void fill_kernel(const int* __restrict__ src,
                                                   const int* __restrict__ dst,
                                                   const int* __restrict__ row_ptr,
                                                   int* __restrict__ cursor,
                                                   int* __restrict__ col) {
    int e = blockIdx.x * 256 + threadIdx.x;
    if (e < NE) {
        int d = dst[e];
        int pos = row_ptr[d] + atomicAdd(&cursor[d], 1);
        col[pos] = src[e];
    }
}

// ---------------- layer-1 gather (F=3), atomic-free ----------------
__global__ __launch_bounds__(256) void gather3_kernel(const int* __restrict__ row_ptr,
                                                      const int* __restrict__ col,
                                                      const float* __restrict__ h0s,
                                                      const float* __restrict__ norm_d,
                                                      float* __restrict__ agg3) {
    int n = blockIdx.x * 256 + threadIdx.x;
    if (n < NN) {
        float a0 = 0.f, a1 = 0.f, a2 = 0.f;
        int end = row_ptr[n + 1];
        for (int e = row_ptr[n]; e < end; ++e) {
            int s = col[e];
            a0 += h0s[s * 3 + 0];
            a1 += h0s[s * 3 + 1];
            a2 += h0s[s * 3 + 2];
        }
        float nd = norm_d[n];
        agg3[n * 3 + 0] = a0 * nd;
        agg3[n * 3 + 1] = a1 * nd;
        agg3[n * 3 + 2] = a2 * nd;
    }
}

// ---------------- layer-1 node (3 -> 128), output pre-scaled by norm_s ----------------
__global__ __launch_bounds__(256) void node3_kernel(const float* __restrict__ agg3,
                                                    const float* __restrict__ norm_s,
                                                    const float* __restrict__ W1,
                                                    const float* __restrict__ b1,
                                                    float* __restrict__ h1s) {
    int gid = blockIdx.x * 256 + threadIdx.x;
    int i = gid >> 7, c = gid & 127;
    if (i < NN) {
        float a0 = agg3[i * 3 + 0];
        float a1 = agg3[i * 3 + 1];
        float a2 = agg3[i * 3 + 2];
        float v = a0 * W1[c] + a1 * W1[128 + c] + a2 * W1[256 + c] + b1[c];
        h1s[i * 128 + c] = fmaxf(v, 0.0f) * norm_s[i];
    }
}

// ---------------- fused layer: CSR gather -> LDS -> GEMM -> relu/scale/store ----------------
// 64 nodes per block, 256 threads = 4 waves. Gather: one WAVE per node (no
// divergence within wave; col[e] is wave-uniform -> scalar loads), lane owns
// 2 features. GEMM: 8x4 register tile per thread as before.
// If embsum != nullptr (last layer): also accumulate column sums.
__global__ __launch_bounds__(256) void fused_layer_kernel(const int* __restrict__ row_ptr,
                                                          const int* __restrict__ col,
                                                          const float* __restrict__ hs,
                                                          const float* __restrict__ norm_d,
                                                          const float* __restrict__ W,
                                                          const float* __restrict__ b,
                                                          const float* __restrict__ scale,
                                                          float* __restrict__ out,
                                                          float* __restrict__ embsum) {
    __shared__ float lds[64][129];
    int t = threadIdx.x;
    int wave = t >> 6;        // 0..3
    int lane = t & 63;
    int row0 = blockIdx.x * 64;
    int c2 = lane << 1;

    // ---- gather phase: wave w handles nodes row0 + w*16 .. +15 ----
    for (int i = 0; i < 16; ++i) {
        int r = (wave << 4) + i;
        int n = row0 + r;
        float ax = 0.f, ay = 0.f;
        if (n < NN) {
            int beg = row_ptr[n], end = row_ptr[n + 1];
            int e = beg;
            for (; e + 1 < end; e += 2) {
                int s0 = col[e], s1 = col[e + 1];
                float2 v0 = *(const float2*)(hs + (long)s0 * HD + c2);
                float2 v1 = *(const float2*)(hs + (long)s1 * HD + c2);
                ax += v0.x + v1.x;
                ay += v0.y + v1.y;
            }
            if (e < end) {
                float2 v0 = *(const float2*)(hs + (long)col[e] * HD + c2);
                ax += v0.x; ay += v0.y;
            }
            float nd = norm_d[n];
            ax *= nd; ay *= nd;
        }
        lds[r][c2] = ax;
        lds[r][c2 + 1] = ay;
    }
    __syncthreads();

    // ---- GEMM phase ----
    int cg = (t & 31) << 2;
    int rg = (t >> 5) << 3;

    float acc[8][4];
    #pragma unroll
    for (int i = 0; i < 8; ++i)
        #pragma unroll
        for (int j = 0; j < 4; ++j)
            acc[i][j] = 0.f;

    for (int k = 0; k < 128; ++k) {
        float4 w = *(const float4*)(W + (long)k * HD + cg);
        #pragma unroll
        for (int i = 0; i < 8; ++i) {
            float a = lds[rg + i][k];
            acc[i][0] += a * w.x;
            acc[i][1] += a * w.y;
            acc[i][2] += a * w.z;
            acc[i][3] += a * w.w;
        }
    }

    float b0 = b[cg + 0], b1 = b[cg + 1], b2 = b[cg + 2], b3 = b[cg + 3];
    float p0 = 0.f, p1 = 0.f, p2 = 0.f, p3 = 0.f;   // colsum partials
    #pragma unroll
    for (int i = 0; i < 8; ++i) {
        int row = row0 + rg + i;
        if (row < NN) {
            float sc = scale ? scale[row] : 1.0f;
            float v0 = fmaxf(acc[i][0] + b0, 0.f);
            float v1 = fmaxf(acc[i][1] + b1, 0.f);
            float v2 = fmaxf(acc[i][2] + b2, 0.f);
            float v3 = fmaxf(acc[i][3] + b3, 0.f);
            float* op = out + (long)row * HD + cg;
            op[0] = v0 * sc;
            op[1] = v1 * sc;
            op[2] = v2 * sc;
            op[3] = v3 * sc;
            p0 += v0; p1 += v1; p2 += v2; p3 += v3;   // unscaled (last layer has scale=null)
        }
    }

    // ---- fused column-sum (last layer only) ----
    if (embsum) {
        __syncthreads();                      // done reading lds as A-tile
        float (*lds2)[128] = (float(*)[128])lds;
        int rb = rg >> 3;                     // 0..7
        lds2[rb][cg + 0] = p0;
        lds2[rb][cg + 1] = p1;
        lds2[rb][cg + 2] = p2;
        lds2[rb][cg + 3] = p3;
        __syncthreads();
        if (t < 128) {
            float s = 0.f;
            #pragma unroll
            for (int r = 0; r < 8; ++r) s += lds2[r][t];
            atomicAdd(&embsum[t], s);
        }
    }
}

// ---------------- head MLP ----------------
__global__ __launch_bounds__(128) void head_kernel(const float* __restrict__ embsum,
                                                   const float* __restrict__ Wl1,
                                                   const float* __restrict__ bl1,
                                                   const float* __restrict__ Wl2,
                                                   const float* __restrict__ bl2,
                                                   float* __restrict__ d_out) {
    __shared__ float emb[128];
    __shared__ float hemb[64];
    int t = threadIdx.x;
    float e = embsum[t] * (1.0f / (float)NN);
    emb[t] = e;
    d_out[1 + t] = e;
    __syncthreads();
    if (t < 64) {
        float acc = bl1[t];
        for (int k = 0; k < 128; ++k)
            acc += emb[k] * Wl1[k * 64 + t];
        hemb[t] = fmaxf(acc, 0.f);
    }
    __syncthreads();
    if (t == 0) {
        float acc = bl2[0];
        for (int j = 0; j < 64; ++j)
            acc += hemb[j] * Wl2[j];
        d_out[0] = 1.0f / (1.0f + expf(-acc));
    }
}

extern "C" void kernel_launch(void* const* d_in, const int* in_sizes, int n_in,
                              void* d_out, int out_size, void* d_ws, size_t ws_size,
                              hipStream_t stream) {
    const float* cx  = (const float*)d_in[0];
    const float* cy  = (const float*)d_in[1];
    const float* W1  = (const float*)d_in[2];
    const float* b1  = (const float*)d_in[3];
    const float* W2  = (const float*)d_in[4];
    const float* b2  = (const float*)d_in[5];
    const float* W3  = (const float*)d_in[6];
    const float* b3  = (const float*)d_in[7];
    const float* W4  = (const float*)d_in[8];
    const float* b4  = (const float*)d_in[9];
    const float* W5  = (const float*)d_in[10];
    const float* b5  = (const float*)d_in[11];
    const float* Wl1 = (const float*)d_in[12];
    const float* bl1 = (const float*)d_in[13];
    const float* Wl2 = (const float*)d_in[14];
    const float* bl2 = (const float*)d_in[15];
    const int*   src = (const int*)d_in[16];
    const int*   dst = (const int*)d_in[17];

    float* out = (float*)d_out;
    float* h_out = out + 129;             // final h lives in d_out

    // workspace layout (floats). CSR must be in ws now: the layer-5 fused
    // kernel reads CSR while other blocks write h_out -> no aliasing allowed.
    float* ws      = (float*)d_ws;
    float* norm_s  = ws;                   // N
    float* norm_d  = ws + NN;              // N
    float* in_deg  = ws + 2 * NN;          // N (counts; dead after rowptr)
    float* out_deg = ws + 3 * NN;          // N (dead after init -> cursor)
    int*   cursor  = (int*)out_deg;
    float* hs      = ws + 4 * NN;          // 128N
    int*   row_ptr = (int*)(ws + 132 * NN);        // N+1 ints
    int*   col     = (int*)(ws + 133 * NN + 256);  // E ints (padded past row_ptr)
    float* h0s     = ws + 150 * NN;        // 3N
    float* agg3    = ws + 153 * NN;        // 3N
    float* embsum  = ws + 156 * NN;        // 128
    int*   bsums   = (int*)(ws + 156 * NN + 128);  // SCAN_BLOCKS ints

    // 1. degrees
    hipMemsetAsync(in_deg, 0, 2 * NN * sizeof(float), stream);
    deg_kernel<<<(NE + 255) / 256, 256, 0, stream>>>(src, dst, in_deg, out_deg);

    // 2. norms + scaled h0
    node_init_kernel<<<(NN + 255) / 256, 256, 0, stream>>>(cx, cy, in_deg, out_deg,
                                                           norm_s, norm_d, h0s);

    // 3. CSR build (3-pass parallel scan + bucket scatter)
    blocksum_kernel<<<SCAN_BLOCKS, 256, 0, stream>>>(in_deg, bsums);
    scan_sums_kernel<<<1, 256, 0, stream>>>(bsums);
    rowptr_kernel<<<SCAN_BLOCKS, 256, 0, stream>>>(in_deg, bsums, row_ptr);
    hipMemsetAsync(cursor, 0, NN * sizeof(int), stream);
    fill_kernel<<<(NE + 255) / 256, 256, 0, stream>>>(src, dst, row_ptr, cursor, col);

    // 4. layer 1 (F_in = 3)
    gather3_kernel<<<(NN + 255) / 256, 256, 0, stream>>>(row_ptr, col, h0s, norm_d, agg3);
    node3_kernel<<<(NN * 128) / 256, 256, 0, stream>>>(agg3, norm_s, W1, b1, hs);

    // 5. layers 2..5: fused gather+GEMM (+ colsum on last)
    hipMemsetAsync(embsum, 0, 128 * sizeof(float), stream);
    const float* Ws[4] = {W2, W3, W4, W5};
    const float* bs[4] = {b2, b3, b4, b5};
    const int fused_blocks = (NN + 63) / 64;
    for (int l = 0; l < 4; ++l) {
        float* dst_h = (l == 3) ? h_out : hs;
        const float* sc = (l == 3) ? nullptr : norm_s;
        float* es = (l == 3) ? embsum : nullptr;
        fused_layer_kernel<<<fused_blocks, 256, 0, stream>>>(row_ptr, col, hs, norm_d,
                                                             Ws[l], bs[l], sc, dst_h, es);
    }

    // 6. head
    head_kernel<<<1, 128, 0, stream>>>(embsum, Wl1, bl1, Wl2, bl2, out);
}

// Round 5
// 471.710 us; speedup vs baseline: 1.4718x; 1.4718x over previous
//
#include <hip/hip_runtime.h>
#include <hip/hip_bf16.h>
#include <math.h>

#define NN 50000
#define NE 800000
#define HD 128
#define SCAN_BLOCKS ((NN + 255) / 256)   // 196

static __device__ __forceinline__ unsigned short f2bf(float x) {
    union { float f; unsigned u; } v; v.f = x;
    unsigned r = v.u + 0x7fff + ((v.u >> 16) & 1);   // RNE
    return (unsigned short)(r >> 16);
}

// ---------------- degree computation ----------------
__global__ __launch_bounds__(256) void deg_kernel(const int* __restrict__ src,
                                                  const int* __restrict__ dst,
                                                  float* __restrict__ in_deg,
                                                  float* __restrict__ out_deg) {
    int e = blockIdx.x * 256 + threadIdx.x;
    if (e < NE) {
        atomicAdd(&in_deg[dst[e]], 1.0f);
        atomicAdd(&out_deg[src[e]], 1.0f);
    }
}

// ---------------- node init: norms + h0 pre-scaled by norm_s ----------------
__global__ __launch_bounds__(256) void node_init_kernel(const float* __restrict__ cx,
                                                        const float* __restrict__ cy,
                                                        const float* __restrict__ in_deg,
                                                        const float* __restrict__ out_deg,
                                                        float* __restrict__ norm_s,
                                                        float* __restrict__ norm_d,
                                                        float* __restrict__ h0s) {
    int i = blockIdx.x * 256 + threadIdx.x;
    if (i < NN) {
        float id = in_deg[i], od = out_deg[i];
        float ns = 1.0f / sqrtf(fmaxf(od, 1.0f));
        norm_s[i] = ns;
        norm_d[i] = 1.0f / sqrtf(fmaxf(id, 1.0f));
        h0s[i * 3 + 0] = id * ns;
        h0s[i * 3 + 1] = cx[i] * ns;
        h0s[i * 3 + 2] = cy[i] * ns;
    }
}

// ---------------- 3-pass parallel exclusive scan of in-degree counts ----------------
__global__ __launch_bounds__(256) void blocksum_kernel(const float* __restrict__ counts,
                                                       int* __restrict__ block_sums) {
    __shared__ int red[256];
    int t = threadIdx.x;
    int i = blockIdx.x * 256 + t;
    red[t] = (i < NN) ? (int)counts[i] : 0;
    __syncthreads();
    #pragma unroll
    for (int off = 128; off > 0; off >>= 1) {
        if (t < off) red[t] += red[t + off];
        __syncthreads();
    }
    if (t == 0) block_sums[blockIdx.x] = red[0];
}

__global__ __launch_bounds__(256) void scan_sums_kernel(int* __restrict__ block_sums) {
    __shared__ int buf[256];
    int t = threadIdx.x;
    int v = (t < SCAN_BLOCKS) ? block_sums[t] : 0;
    buf[t] = v;
    __syncthreads();
    #pragma unroll
    for (int off = 1; off < 256; off <<= 1) {
        int add = (t >= off) ? buf[t - off] : 0;
        __syncthreads();
        buf[t] += add;
        __syncthreads();
    }
    if (t < SCAN_BLOCKS) block_sums[t] = buf[t] - v;   // exclusive
}

__global__ __launch_bounds__(256) void rowptr_kernel(const float* __restrict__ counts,
                                                     const int* __restrict__ block_sums,
                                                     int* __restrict__ row_ptr) {
    __shared__ int buf[256];
    int t = threadIdx.x;
    int i = blockIdx.x * 256 + t;
    int v = (i < NN) ? (int)counts[i] : 0;
    buf[t] = v;
    __syncthreads();
    #pragma unroll
    for (int off = 1; off < 256; off <<= 1) {
        int add = (t >= off) ? buf[t - off] : 0;
        __syncthreads();
        buf[t] += add;
        __syncthreads();
    }
    if (i < NN) row_ptr[i] = block_sums[blockIdx.x] + buf[t] - v;
    if (i == 0) row_ptr[NN] = NE;
}

// ---------------- CSR build: bucket scatter of src ids ----------------
__global__ __launch_bounds__(256) void fill_kernel(const int* __restrict__ src,
                                                   const int* __restrict__ dst,
                                                   const int* __restrict__ row_ptr,
                                                   int* __restrict__ cursor,
                                                   int* __restrict__ col) {
    int e = blockIdx.x * 256 + threadIdx.x;
    if (e < NE) {
        int d = dst[e];
        int pos = row_ptr[d] + atomicAdd(&cursor[d], 1);
        col[pos] = src[e];
    }
}

// ---------------- layer-1 gather (F=3), atomic-free ----------------
__global__ __launch_bounds__(256) void gather3_kernel(const int* __restrict__ row_ptr,
                                                      const int* __restrict__ col,
                                                      const float* __restrict__ h0s,
                                                      const float* __restrict__ norm_d,
                                                      float* __restrict__ agg3) {
    int n = blockIdx.x * 256 + threadIdx.x;
    if (n < NN) {
        float a0 = 0.f, a1 = 0.f, a2 = 0.f;
        int end = row_ptr[n + 1];
        for (int e = row_ptr[n]; e < end; ++e) {
            int s = col[e];
            a0 += h0s[s * 3 + 0];
            a1 += h0s[s * 3 + 1];
            a2 += h0s[s * 3 + 2];
        }
        float nd = norm_d[n];
        agg3[n * 3 + 0] = a0 * nd;
        agg3[n * 3 + 1] = a1 * nd;
        agg3[n * 3 + 2] = a2 * nd;
    }
}

// ---------------- layer-1 node (3 -> 128), bf16 out pre-scaled by norm_s ----------------
__global__ __launch_bounds__(256) void node3_kernel(const float* __restrict__ agg3,
                                                    const float* __restrict__ norm_s,
                                                    const float* __restrict__ W1,
                                                    const float* __restrict__ b1,
                                                    unsigned short* __restrict__ h1s) {
    int gid = blockIdx.x * 256 + threadIdx.x;
    int i = gid >> 7, c = gid & 127;
    if (i < NN) {
        float a0 = agg3[i * 3 + 0];
        float a1 = agg3[i * 3 + 1];
        float a2 = agg3[i * 3 + 2];
        float v = a0 * W1[c] + a1 * W1[128 + c] + a2 * W1[256 + c] + b1[c];
        h1s[i * 128 + c] = f2bf(fmaxf(v, 0.0f) * norm_s[i]);
    }
}

// ---------------- edge aggregation F=128: bf16 CSR gather, atomic-free ----------------
// One WAVE per node (wave-uniform edge loop, zero divergence). Lane owns 2
// features = one packed bf16x2 dword. 4 waves / block. Unroll 4 for MLP.
__global__ __launch_bounds__(256) void gather_bf16_kernel(const int* __restrict__ row_ptr,
                                                          const int* __restrict__ col,
                                                          const unsigned int* __restrict__ hs2,
                                                          const float* __restrict__ norm_d,
                                                          float* __restrict__ agg) {
    int t = threadIdx.x;
    int wave = t >> 6;
    int lane = t & 63;
    int n = blockIdx.x * 4 + wave;
    if (n >= NN) return;
    int beg = row_ptr[n], end = row_ptr[n + 1];
    const unsigned int* base = hs2 + lane;     // row stride 64 dwords
    float ax = 0.f, ay = 0.f;
    int e = beg;
    for (; e + 3 < end; e += 4) {
        int s0 = col[e], s1 = col[e + 1], s2 = col[e + 2], s3 = col[e + 3];
        unsigned u0 = base[(long)s0 << 6];
        unsigned u1 = base[(long)s1 << 6];
        unsigned u2 = base[(long)s2 << 6];
        unsigned u3 = base[(long)s3 << 6];
        ax += __uint_as_float(u0 << 16) + __uint_as_float(u1 << 16)
            + __uint_as_float(u2 << 16) + __uint_as_float(u3 << 16);
        ay += __uint_as_float(u0 & 0xffff0000u) + __uint_as_float(u1 & 0xffff0000u)
            + __uint_as_float(u2 & 0xffff0000u) + __uint_as_float(u3 & 0xffff0000u);
    }
    for (; e < end; ++e) {
        unsigned u0 = base[(long)col[e] << 6];
        ax += __uint_as_float(u0 << 16);
        ay += __uint_as_float(u0 & 0xffff0000u);
    }
    float nd = norm_d[n];
    *(float2*)(agg + (long)n * HD + (lane << 1)) = make_float2(ax * nd, ay * nd);
}

// ---------------- node GEMM: relu(agg @ W + b) -> bf16 hs  OR fp32 h_out ----------------
// Exactly one of out_bf / out_f32 is non-null. embsum non-null on final layer
// -> fused column-sum of the (unscaled) relu outputs.
__global__ __launch_bounds__(256) void gemm_node_kernel(const float* __restrict__ agg,
                                                        const float* __restrict__ scale,
                                                        const float* __restrict__ W,
                                                        const float* __restrict__ b,
                                                        unsigned short* __restrict__ out_bf,
                                                        float* __restrict__ out_f32,
                                                        float* __restrict__ embsum) {
    __shared__ float lds[64][129];
    int row0 = blockIdx.x * 64;
    int t = threadIdx.x;

    #pragma unroll
    for (int i = 0; i < 8; ++i) {
        int idx = t + 256 * i;
        int r = idx >> 5;
        int c4 = (idx & 31) << 2;
        int row = row0 + r;
        float4 v = make_float4(0.f, 0.f, 0.f, 0.f);
        if (row < NN)
            v = *(const float4*)(agg + (long)row * HD + c4);
        lds[r][c4 + 0] = v.x;
        lds[r][c4 + 1] = v.y;
        lds[r][c4 + 2] = v.z;
        lds[r][c4 + 3] = v.w;
    }
    __syncthreads();

    int cg = (t & 31) << 2;
    int rg = (t >> 5) << 3;

    float acc[8][4];
    #pragma unroll
    for (int i = 0; i < 8; ++i)
        #pragma unroll
        for (int j = 0; j < 4; ++j)
            acc[i][j] = 0.f;

    for (int k = 0; k < 128; ++k) {
        float4 w = *(const float4*)(W + (long)k * HD + cg);
        #pragma unroll
        for (int i = 0; i < 8; ++i) {
            float a = lds[rg + i][k];
            acc[i][0] += a * w.x;
            acc[i][1] += a * w.y;
            acc[i][2] += a * w.z;
            acc[i][3] += a * w.w;
        }
    }

    float b0 = b[cg + 0], b1 = b[cg + 1], b2 = b[cg + 2], b3 = b[cg + 3];
    float p0 = 0.f, p1 = 0.f, p2 = 0.f, p3 = 0.f;
    #pragma unroll
    for (int i = 0; i < 8; ++i) {
        int row = row0 + rg + i;
        if (row < NN) {
            float v0 = fmaxf(acc[i][0] + b0, 0.f);
            float v1 = fmaxf(acc[i][1] + b1, 0.f);
            float v2 = fmaxf(acc[i][2] + b2, 0.f);
            float v3 = fmaxf(acc[i][3] + b3, 0.f);
            if (out_bf) {
                float sc = scale[row];
                ushort4 o;
                o.x = f2bf(v0 * sc);
                o.y = f2bf(v1 * sc);
                o.z = f2bf(v2 * sc);
                o.w = f2bf(v3 * sc);
                *(ushort4*)(out_bf + (long)row * HD + cg) = o;
            } else {
                float* op = out_f32 + (long)row * HD + cg;
                op[0] = v0; op[1] = v1; op[2] = v2; op[3] = v3;
            }
            p0 += v0; p1 += v1; p2 += v2; p3 += v3;
        }
    }

    if (embsum) {
        __syncthreads();
        float (*lds2)[128] = (float(*)[128])lds;
        int rb = rg >> 3;
        lds2[rb][cg + 0] = p0;
        lds2[rb][cg + 1] = p1;
        lds2[rb][cg + 2] = p2;
        lds2[rb][cg + 3] = p3;
        __syncthreads();
        if (t < 128) {
            float s = 0.f;
            #pragma unroll
            for (int r = 0; r < 8; ++r) s += lds2[r][t];
            atomicAdd(&embsum[t], s);
        }
    }
}

// ---------------- head MLP ----------------
__global__ __launch_bounds__(128) void head_kernel(const float* __restrict__ embsum,
                                                   const float* __restrict__ Wl1,
                                                   const float* __restrict__ bl1,
                                                   const float* __restrict__ Wl2,
                                                   const float* __restrict__ bl2,
                                                   float* __restrict__ d_out) {
    __shared__ float emb[128];
    __shared__ float hemb[64];
    int t = threadIdx.x;
    float e = embsum[t] * (1.0f / (float)NN);
    emb[t] = e;
    d_out[1 + t] = e;
    __syncthreads();
    if (t < 64) {
        float acc = bl1[t];
        for (int k = 0; k < 128; ++k)
            acc += emb[k] * Wl1[k * 64 + t];
        hemb[t] = fmaxf(acc, 0.f);
    }
    __syncthreads();
    if (t == 0) {
        float acc = bl2[0];
        for (int j = 0; j < 64; ++j)
            acc += hemb[j] * Wl2[j];
        d_out[0] = 1.0f / (1.0f + expf(-acc));
    }
}

extern "C" void kernel_launch(void* const* d_in, const int* in_sizes, int n_in,
                              void* d_out, int out_size, void* d_ws, size_t ws_size,
                              hipStream_t stream) {
    const float* cx  = (const float*)d_in[0];
    const float* cy  = (const float*)d_in[1];
    const float* W1  = (const float*)d_in[2];
    const float* b1  = (const float*)d_in[3];
    const float* W2  = (const float*)d_in[4];
    const float* b2  = (const float*)d_in[5];
    const float* W3  = (const float*)d_in[6];
    const float* b3  = (const float*)d_in[7];
    const float* W4  = (const float*)d_in[8];
    const float* b4  = (const float*)d_in[9];
    const float* W5  = (const float*)d_in[10];
    const float* b5  = (const float*)d_in[11];
    const float* Wl1 = (const float*)d_in[12];
    const float* bl1 = (const float*)d_in[13];
    const float* Wl2 = (const float*)d_in[14];
    const float* bl2 = (const float*)d_in[15];
    const int*   src = (const int*)d_in[16];
    const int*   dst = (const int*)d_in[17];

    float* out = (float*)d_out;
    float* h_out = out + 129;

    // workspace layout (float units)
    float* ws      = (float*)d_ws;
    float* norm_s  = ws;                    // N
    float* norm_d  = ws + NN;               // N
    float* in_deg  = ws + 2 * NN;           // N
    float* out_deg = ws + 3 * NN;           // N (-> cursor)
    int*   cursor  = (int*)out_deg;
    unsigned short* hs = (unsigned short*)(ws + 4 * NN);   // 128N bf16 = 64N floats
    float* agg     = ws + 68 * NN;          // 128N
    int*   row_ptr = (int*)(ws + 196 * NN);         // N+1
    int*   col     = (int*)(ws + 197 * NN + 256);   // E
    float* h0s     = ws + 214 * NN;         // 3N
    float* agg3    = ws + 217 * NN;         // 3N
    float* embsum  = ws + 220 * NN;         // 128
    int*   bsums   = (int*)(ws + 220 * NN + 128);

    // 1. degrees
    hipMemsetAsync(in_deg, 0, 2 * NN * sizeof(float), stream);
    deg_kernel<<<(NE + 255) / 256, 256, 0, stream>>>(src, dst, in_deg, out_deg);

    // 2. norms + scaled h0
    node_init_kernel<<<(NN + 255) / 256, 256, 0, stream>>>(cx, cy, in_deg, out_deg,
                                                           norm_s, norm_d, h0s);

    // 3. CSR build
    blocksum_kernel<<<SCAN_BLOCKS, 256, 0, stream>>>(in_deg, bsums);
    scan_sums_kernel<<<1, 256, 0, stream>>>(bsums);
    rowptr_kernel<<<SCAN_BLOCKS, 256, 0, stream>>>(in_deg, bsums, row_ptr);
    hipMemsetAsync(cursor, 0, NN * sizeof(int), stream);
    fill_kernel<<<(NE + 255) / 256, 256, 0, stream>>>(src, dst, row_ptr, cursor, col);

    // 4. layer 1 (F_in = 3)
    gather3_kernel<<<(NN + 255) / 256, 256, 0, stream>>>(row_ptr, col, h0s, norm_d, agg3);
    node3_kernel<<<(NN * 128) / 256, 256, 0, stream>>>(agg3, norm_s, W1, b1, hs);

    // 5. layers 2..5: bf16 gather + fp32 GEMM (+ fused colsum on last)
    hipMemsetAsync(embsum, 0, 128 * sizeof(float), stream);
    const float* Ws[4] = {W2, W3, W4, W5};
    const float* bs[4] = {b2, b3, b4, b5};
    const int gather_blocks = (NN + 3) / 4;
    const int gemm_blocks = (NN + 63) / 64;
    for (int l = 0; l < 4; ++l) {
        gather_bf16_kernel<<<gather_blocks, 256, 0, stream>>>(row_ptr, col,
                                                              (const unsigned int*)hs,
                                                              norm_d, agg);
        bool last = (l == 3);
        gemm_node_kernel<<<gemm_blocks, 256, 0, stream>>>(
            agg, norm_s, Ws[l], bs[l],
            last ? nullptr : hs,
            last ? h_out : nullptr,
            last ? embsum : nullptr);
    }

    // 6. head
    head_kernel<<<1, 128, 0, stream>>>(embsum, Wl1, bl1, Wl2, bl2, out);
}

// Round 6
// 365.175 us; speedup vs baseline: 1.9012x; 1.2917x over previous
//
#include <hip/hip_runtime.h>
#include <hip/hip_bf16.h>
#include <math.h>

#define NN 50000
#define NE 800000
#define HD 128
#define MAXDEG 64

typedef __attribute__((ext_vector_type(8))) short bf16x8v;   // 8 bf16 (4 VGPRs)
typedef __attribute__((ext_vector_type(4))) float f32x4v;    // MFMA acc

static __device__ __forceinline__ unsigned short f2bf(float x) {
    union { float f; unsigned u; } v; v.f = x;
    unsigned r = v.u + 0x7fff + ((v.u >> 16) & 1);   // RNE
    return (unsigned short)(r >> 16);
}

// ---------------- one-pass padded-CSR build + both degree histograms ----------------
// fill's returning atomic IS the in-degree histogram; padded col avoids scan.
__global__ __launch_bounds__(256) void build_kernel(const int* __restrict__ src,
                                                    const int* __restrict__ dst,
                                                    int* __restrict__ in_cnt,
                                                    int* __restrict__ out_cnt,
                                                    int* __restrict__ col) {
    int e = blockIdx.x * 256 + threadIdx.x;
    if (e < NE) {
        int d = dst[e], s = src[e];
        int pos = atomicAdd(&in_cnt[d], 1);
        if (pos < MAXDEG) col[(d << 6) + pos] = s;   // P(deg>=64) ~ 1e-18 @ Poisson(16)
        atomicAdd(&out_cnt[s], 1);
    }
}

// ---------------- node init: norms + h0 pre-scaled by norm_s ----------------
__global__ __launch_bounds__(256) void node_init_kernel(const float* __restrict__ cx,
                                                        const float* __restrict__ cy,
                                                        const int* __restrict__ in_cnt,
                                                        const int* __restrict__ out_cnt,
                                                        float* __restrict__ norm_s,
                                                        float* __restrict__ norm_d,
                                                        float* __restrict__ h0s) {
    int i = blockIdx.x * 256 + threadIdx.x;
    if (i < NN) {
        float id = (float)in_cnt[i], od = (float)out_cnt[i];
        float ns = 1.0f / sqrtf(fmaxf(od, 1.0f));
        norm_s[i] = ns;
        norm_d[i] = 1.0f / sqrtf(fmaxf(id, 1.0f));
        h0s[i * 3 + 0] = id * ns;
        h0s[i * 3 + 1] = cx[i] * ns;
        h0s[i * 3 + 2] = cy[i] * ns;
    }
}

// ---------------- W2..W5 -> bf16, transposed: Wt[l][n][k] = bf16(W[k][n]) ----------------
__global__ __launch_bounds__(256) void convw_kernel(const float* __restrict__ W2,
                                                    const float* __restrict__ W3,
                                                    const float* __restrict__ W4,
                                                    const float* __restrict__ W5,
                                                    unsigned short* __restrict__ Wt) {
    int gid = blockIdx.x * 256 + threadIdx.x;
    if (gid < 4 * 16384) {
        int l = gid >> 14, idx = gid & 16383;
        int n = idx >> 7, k = idx & 127;
        const float* W = (l == 0) ? W2 : (l == 1) ? W3 : (l == 2) ? W4 : W5;
        Wt[gid] = f2bf(W[k * 128 + n]);
    }
}

// ---------------- layer-1 gather (F=3), padded CSR ----------------
__global__ __launch_bounds__(256) void gather3_kernel(const int* __restrict__ in_cnt,
                                                      const int* __restrict__ col,
                                                      const float* __restrict__ h0s,
                                                      const float* __restrict__ norm_d,
                                                      float* __restrict__ agg3) {
    int n = blockIdx.x * 256 + threadIdx.x;
    if (n < NN) {
        int cnt = min(in_cnt[n], MAXDEG);
        int base = n << 6;
        float a0 = 0.f, a1 = 0.f, a2 = 0.f;
        for (int e = 0; e < cnt; ++e) {
            int s = col[base + e];
            a0 += h0s[s * 3 + 0];
            a1 += h0s[s * 3 + 1];
            a2 += h0s[s * 3 + 2];
        }
        float nd = norm_d[n];
        agg3[n * 3 + 0] = a0 * nd;
        agg3[n * 3 + 1] = a1 * nd;
        agg3[n * 3 + 2] = a2 * nd;
    }
}

// ---------------- layer-1 node (3 -> 128), bf16 out pre-scaled by norm_s ----------------
__global__ __launch_bounds__(256) void node3_kernel(const float* __restrict__ agg3,
                                                    const float* __restrict__ norm_s,
                                                    const float* __restrict__ W1,
                                                    const float* __restrict__ b1,
                                                    unsigned short* __restrict__ h1s) {
    int gid = blockIdx.x * 256 + threadIdx.x;
    int i = gid >> 7, c = gid & 127;
    if (i < NN) {
        float a0 = agg3[i * 3 + 0];
        float a1 = agg3[i * 3 + 1];
        float a2 = agg3[i * 3 + 2];
        float v = a0 * W1[c] + a1 * W1[128 + c] + a2 * W1[256 + c] + b1[c];
        h1s[i * 128 + c] = f2bf(fmaxf(v, 0.0f) * norm_s[i]);
    }
}

// ---------------- edge aggregation F=128: bf16 gather -> bf16 agg ----------------
// One WAVE per node (wave-uniform edge loop). Lane owns 2 features (1 dword).
__global__ __launch_bounds__(256) void gather_bf16_kernel(const int* __restrict__ in_cnt,
                                                          const int* __restrict__ col,
                                                          const unsigned int* __restrict__ hs2,
                                                          const float* __restrict__ norm_d,
                                                          unsigned int* __restrict__ aggb2) {
    int t = threadIdx.x;
    int wave = t >> 6;
    int lane = t & 63;
    int n = blockIdx.x * 4 + wave;
    if (n >= NN) return;
    int cnt = min(in_cnt[n], MAXDEG);
    int base = n << 6;
    const unsigned int* hb = hs2 + lane;
    float ax = 0.f, ay = 0.f;
    int e = 0;
    for (; e + 3 < cnt; e += 4) {
        int s0 = col[base + e], s1 = col[base + e + 1];
        int s2 = col[base + e + 2], s3 = col[base + e + 3];
        unsigned u0 = hb[(long)s0 << 6];
        unsigned u1 = hb[(long)s1 << 6];
        unsigned u2 = hb[(long)s2 << 6];
        unsigned u3 = hb[(long)s3 << 6];
        ax += __uint_as_float(u0 << 16) + __uint_as_float(u1 << 16)
            + __uint_as_float(u2 << 16) + __uint_as_float(u3 << 16);
        ay += __uint_as_float(u0 & 0xffff0000u) + __uint_as_float(u1 & 0xffff0000u)
            + __uint_as_float(u2 & 0xffff0000u) + __uint_as_float(u3 & 0xffff0000u);
    }
    for (; e < cnt; ++e) {
        unsigned u0 = hb[(long)col[base + e] << 6];
        ax += __uint_as_float(u0 << 16);
        ay += __uint_as_float(u0 & 0xffff0000u);
    }
    float nd = norm_d[n];
    unsigned po = (unsigned)f2bf(ax * nd) | ((unsigned)f2bf(ay * nd) << 16);
    aggb2[(n << 6) + lane] = po;
}

// ---------------- node GEMM via MFMA bf16: relu(aggb @ W + b) ----------------
// 64 rows/block, 4 waves (16 rows each). A-frags from global aggb (L2-hot),
// B-frags from LDS-staged Wt[n][k] (pad +8 bf16 -> 2-way banks, free).
// D mapping (m89-verified): col = lane&15, row = (lane>>4)*4 + reg.
__global__ __launch_bounds__(256) void gemm_mfma_kernel(const unsigned short* __restrict__ aggb,
                                                        const float* __restrict__ scale,
                                                        const unsigned short* __restrict__ Wt,
                                                        const float* __restrict__ bias,
                                                        unsigned short* __restrict__ out_bf,
                                                        float* __restrict__ out_f32,
                                                        float* __restrict__ embsum) {
    __shared__ unsigned short ldsw[128][136];
    __shared__ float ldscol[4][4][128];

    int t = threadIdx.x;
    int wv = t >> 6, lane = t & 63;
    int fr = lane & 15, kq = lane >> 4;
    int m0 = blockIdx.x * 64 + wv * 16;

    // stage Wt (32 KB) into LDS, coalesced 16B per lane
    #pragma unroll
    for (int i = 0; i < 8; ++i) {
        int idx = t + 256 * i;          // 2048 chunks of 8 bf16
        int r = idx >> 4;
        int c8 = (idx & 15) << 3;
        *(bf16x8v*)(&ldsw[r][c8]) = *(const bf16x8v*)(Wt + (r << 7) + c8);
    }

    // A fragments: lane holds A[m0+fr][kq*8 + j] for each 32-wide K block
    int mrow = m0 + fr;
    long abase = (long)((mrow < NN) ? mrow : 0) << 7;
    bf16x8v a0 = *(const bf16x8v*)(aggb + abase + 0  + kq * 8);
    bf16x8v a1 = *(const bf16x8v*)(aggb + abase + 32 + kq * 8);
    bf16x8v a2 = *(const bf16x8v*)(aggb + abase + 64 + kq * 8);
    bf16x8v a3 = *(const bf16x8v*)(aggb + abase + 96 + kq * 8);

    // per-lane output rows / scales
    float sc[4];
    #pragma unroll
    for (int r = 0; r < 4; ++r) {
        int mr = m0 + kq * 4 + r;
        sc[r] = (out_bf && mr < NN) ? scale[mr] : 1.0f;
    }

    __syncthreads();

    #pragma unroll
    for (int nt = 0; nt < 8; ++nt) {
        int n0 = nt << 4;
        f32x4v acc = {0.f, 0.f, 0.f, 0.f};
        acc = __builtin_amdgcn_mfma_f32_16x16x32_bf16(a0, *(const bf16x8v*)(&ldsw[n0 + fr][0  + kq * 8]), acc, 0, 0, 0);
        acc = __builtin_amdgcn_mfma_f32_16x16x32_bf16(a1, *(const bf16x8v*)(&ldsw[n0 + fr][32 + kq * 8]), acc, 0, 0, 0);
        acc = __builtin_amdgcn_mfma_f32_16x16x32_bf16(a2, *(const bf16x8v*)(&ldsw[n0 + fr][64 + kq * 8]), acc, 0, 0, 0);
        acc = __builtin_amdgcn_mfma_f32_16x16x32_bf16(a3, *(const bf16x8v*)(&ldsw[n0 + fr][96 + kq * 8]), acc, 0, 0, 0);

        float bv = bias[n0 + fr];
        float cs = 0.f;
        #pragma unroll
        for (int r = 0; r < 4; ++r) {
            int mr = m0 + kq * 4 + r;
            if (mr < NN) {
                float v = fmaxf(acc[r] + bv, 0.f);
                if (out_bf) out_bf[((long)mr << 7) + n0 + fr] = f2bf(v * sc[r]);
                else        out_f32[((long)mr << 7) + n0 + fr] = v;
                cs += v;
            }
        }
        if (embsum) ldscol[wv][kq][n0 + fr] = cs;   // bijective slots, no race
    }

    if (embsum) {
        __syncthreads();
        if (t < 128) {
            float s = 0.f;
            #pragma unroll
            for (int w = 0; w < 4; ++w)
                #pragma unroll
                for (int q = 0; q < 4; ++q)
                    s += ldscol[w][q][t];
            atomicAdd(&embsum[t], s);
        }
    }
}

// ---------------- head MLP ----------------
__global__ __launch_bounds__(128) void head_kernel(const float* __restrict__ embsum,
                                                   const float* __restrict__ Wl1,
                                                   const float* __restrict__ bl1,
                                                   const float* __restrict__ Wl2,
                                                   const float* __restrict__ bl2,
                                                   float* __restrict__ d_out) {
    __shared__ float emb[128];
    __shared__ float hemb[64];
    int t = threadIdx.x;
    float e = embsum[t] * (1.0f / (float)NN);
    emb[t] = e;
    d_out[1 + t] = e;
    __syncthreads();
    if (t < 64) {
        float acc = bl1[t];
        for (int k = 0; k < 128; ++k)
            acc += emb[k] * Wl1[k * 64 + t];
        hemb[t] = fmaxf(acc, 0.f);
    }
    __syncthreads();
    if (t == 0) {
        float acc = bl2[0];
        for (int j = 0; j < 64; ++j)
            acc += hemb[j] * Wl2[j];
        d_out[0] = 1.0f / (1.0f + expf(-acc));
    }
}

extern "C" void kernel_launch(void* const* d_in, const int* in_sizes, int n_in,
                              void* d_out, int out_size, void* d_ws, size_t ws_size,
                              hipStream_t stream) {
    const float* cx  = (const float*)d_in[0];
    const float* cy  = (const float*)d_in[1];
    const float* W1  = (const float*)d_in[2];
    const float* b1  = (const float*)d_in[3];
    const float* W2  = (const float*)d_in[4];
    const float* b2  = (const float*)d_in[5];
    const float* W3  = (const float*)d_in[6];
    const float* b3  = (const float*)d_in[7];
    const float* W4  = (const float*)d_in[8];
    const float* b4  = (const float*)d_in[9];
    const float* W5  = (const float*)d_in[10];
    const float* b5  = (const float*)d_in[11];
    const float* Wl1 = (const float*)d_in[12];
    const float* bl1 = (const float*)d_in[13];
    const float* Wl2 = (const float*)d_in[14];
    const float* bl2 = (const float*)d_in[15];
    const int*   src = (const int*)d_in[16];
    const int*   dst = (const int*)d_in[17];

    float* out = (float*)d_out;
    float* h_out = out + 129;

    // workspace layout (float units)
    float* ws      = (float*)d_ws;
    float* norm_s  = ws;                                // N
    float* norm_d  = ws + NN;                           // N
    int*   in_cnt  = (int*)(ws + 2 * NN);               // N
    int*   out_cnt = (int*)(ws + 3 * NN);               // N
    unsigned short* hs   = (unsigned short*)(ws + 4 * NN);    // 128N bf16 = 64N fl
    unsigned short* aggb = (unsigned short*)(ws + 68 * NN);   // 128N bf16 = 64N fl
    int*   col     = (int*)(ws + 132 * NN);             // 64N (padded CSR)
    float* h0s     = ws + 196 * NN;                     // 3N
    float* agg3    = ws + 199 * NN;                     // 3N
    unsigned short* Wt = (unsigned short*)(ws + 202 * NN);    // 4*16384 bf16
    float* embsum  = ws + 202 * NN + 32768;             // 128

    // 1. padded CSR + degrees (single pass)
    hipMemsetAsync(in_cnt, 0, 2 * NN * sizeof(int), stream);
    build_kernel<<<(NE + 255) / 256, 256, 0, stream>>>(src, dst, in_cnt, out_cnt, col);

    // 2. norms + scaled h0; weight convert (independent)
    node_init_kernel<<<(NN + 255) / 256, 256, 0, stream>>>(cx, cy, in_cnt, out_cnt,
                                                           norm_s, norm_d, h0s);
    convw_kernel<<<256, 256, 0, stream>>>(W2, W3, W4, W5, Wt);

    // 3. layer 1 (F_in = 3)
    gather3_kernel<<<(NN + 255) / 256, 256, 0, stream>>>(in_cnt, col, h0s, norm_d, agg3);
    node3_kernel<<<(NN * 128) / 256, 256, 0, stream>>>(agg3, norm_s, W1, b1, hs);

    // 4. layers 2..5: bf16 gather + MFMA GEMM (+ fused colsum on last)
    hipMemsetAsync(embsum, 0, 128 * sizeof(float), stream);
    const float* Ws[4] = {W2, W3, W4, W5};  (void)Ws;
    const float* bs[4] = {b2, b3, b4, b5};
    const int gather_blocks = (NN + 3) / 4;
    const int gemm_blocks = (NN + 63) / 64;
    for (int l = 0; l < 4; ++l) {
        gather_bf16_kernel<<<gather_blocks, 256, 0, stream>>>(in_cnt, col,
                                                              (const unsigned int*)hs,
                                                              norm_d,
                                                              (unsigned int*)aggb);
        bool last = (l == 3);
        gemm_mfma_kernel<<<gemm_blocks, 256, 0, stream>>>(
            aggb, norm_s, Wt + l * 16384, bs[l],
            last ? nullptr : hs,
            last ? h_out : nullptr,
            last ? embsum : nullptr);
    }

    // 5. head
    head_kernel<<<1, 128, 0, stream>>>(embsum, Wl1, bl1, Wl2, bl2, out);
}

// Round 7
// 343.141 us; speedup vs baseline: 2.0233x; 1.0642x over previous
//
#include <hip/hip_runtime.h>
#include <hip/hip_bf16.h>
#include <math.h>

#define NN 50000
#define NE 800000
#define HD 128
#define NB 196        // coarse buckets: id >> 8  (196*256 = 50176 >= NN)
#define CAP 5120      // per-bucket edge capacity (avg 4082, +16 sigma)
#define B1_EPB 1024   // edges per block in bucket_kernel

typedef __attribute__((ext_vector_type(8))) short bf16x8v;   // 8 bf16 (4 VGPRs)
typedef __attribute__((ext_vector_type(4))) float f32x4v;    // MFMA acc

static __device__ __forceinline__ unsigned short f2bf(float x) {
    union { float f; unsigned u; } v; v.f = x;
    unsigned r = v.u + 0x7fff + ((v.u >> 16) & 1);   // RNE
    return (unsigned short)(r >> 16);
}

// ---------------- B1: coarse bucket scatter (dst-major pairs + src ids) ----------------
__global__ __launch_bounds__(256) void bucket_kernel(const int* __restrict__ src,
                                                     const int* __restrict__ dst,
                                                     int* __restrict__ dcur,
                                                     int* __restrict__ scur,
                                                     int2* __restrict__ dbucket,
                                                     int* __restrict__ sbucket) {
    __shared__ int hd[NB], hsb[NB], cd[NB], cs[NB];
    int t = threadIdx.x;
    if (t < NB) { hd[t] = 0; hsb[t] = 0; }
    __syncthreads();
    int d[4], s[4];
    int e0 = blockIdx.x * B1_EPB + t;
    #pragma unroll
    for (int j = 0; j < 4; ++j) {
        int e = e0 + j * 256;
        if (e < NE) {
            d[j] = dst[e]; s[j] = src[e];
            atomicAdd(&hd[d[j] >> 8], 1);
            atomicAdd(&hsb[s[j] >> 8], 1);
        } else d[j] = -1;
    }
    __syncthreads();
    if (t < NB) {
        cd[t] = atomicAdd(&dcur[t], hd[t]);   // reserve block's chunk per bucket
        cs[t] = atomicAdd(&scur[t], hsb[t]);
    }
    __syncthreads();
    #pragma unroll
    for (int j = 0; j < 4; ++j) {
        if (d[j] >= 0) {
            int b = d[j] >> 8;
            int p = atomicAdd(&cd[b], 1);
            if (p < CAP) dbucket[(long)b * CAP + p] = make_int2(d[j], s[j]);
            int bs = s[j] >> 8;
            int p2 = atomicAdd(&cs[bs], 1);
            if (p2 < CAP) sbucket[(long)bs * CAP + p2] = s[j];
        }
    }
}

// ---------------- B2: per-bucket histogram+scan -> compact CSR (row_ptr, col) ----------------
__global__ __launch_bounds__(256) void csr_dst_kernel(const int2* __restrict__ dbucket,
                                                      const int* __restrict__ dcur,
                                                      int* __restrict__ row_ptr,
                                                      int* __restrict__ col) {
    __shared__ int buf[256];
    __shared__ int hist[256];
    __shared__ int cur[256];
    int k = blockIdx.x, t = threadIdx.x;

    // global base for this bucket: inclusive scan of all bucket totals
    int tot = (t < NB) ? min(dcur[t], CAP) : 0;
    buf[t] = tot;
    __syncthreads();
    for (int o = 1; o < 256; o <<= 1) {
        int a = (t >= o) ? buf[t - o] : 0;
        __syncthreads();
        buf[t] += a;
        __syncthreads();
    }
    int base = (k > 0) ? buf[k - 1] : 0;
    int cnt = min(dcur[k], CAP);

    // 256-bin histogram of dst & 255
    hist[t] = 0;
    __syncthreads();
    const int2* bk = dbucket + (long)k * CAP;
    for (int e = t; e < cnt; e += 256) atomicAdd(&hist[bk[e].x & 255], 1);
    __syncthreads();
    int h = hist[t];

    // exclusive scan of hist
    buf[t] = h;
    __syncthreads();
    for (int o = 1; o < 256; o <<= 1) {
        int a = (t >= o) ? buf[t - o] : 0;
        __syncthreads();
        buf[t] += a;
        __syncthreads();
    }
    int start = base + buf[t] - h;
    int id = (k << 8) + t;
    if (id < NN) row_ptr[id] = start;
    if (k == NB - 1 && t == 0) row_ptr[NN] = base + cnt;   // == NE
    cur[t] = start;
    __syncthreads();

    // scatter src ids into compact col (LDS cursor atomics only)
    for (int e = t; e < cnt; e += 256) {
        int2 p = bk[e];
        int pos = atomicAdd(&cur[p.x & 255], 1);
        col[pos] = p.y;
    }
}

// ---------------- B3: per-bucket src histogram -> out_cnt ----------------
__global__ __launch_bounds__(256) void outdeg_kernel(const int* __restrict__ sbucket,
                                                     const int* __restrict__ scur,
                                                     int* __restrict__ out_cnt) {
    __shared__ int hist[256];
    int k = blockIdx.x, t = threadIdx.x;
    hist[t] = 0;
    __syncthreads();
    int cnt = min(scur[k], CAP);
    const int* bk = sbucket + (long)k * CAP;
    for (int e = t; e < cnt; e += 256) atomicAdd(&hist[bk[e] & 255], 1);
    __syncthreads();
    int id = (k << 8) + t;
    if (id < NN) out_cnt[id] = hist[t];
}

// ---------------- node init: norms + h0 pre-scaled by norm_s ----------------
__global__ __launch_bounds__(256) void node_init_kernel(const float* __restrict__ cx,
                                                        const float* __restrict__ cy,
                                                        const int* __restrict__ row_ptr,
                                                        const int* __restrict__ out_cnt,
                                                        float* __restrict__ norm_s,
                                                        float* __restrict__ norm_d,
                                                        float* __restrict__ h0s) {
    int i = blockIdx.x * 256 + threadIdx.x;
    if (i < NN) {
        float id = (float)(row_ptr[i + 1] - row_ptr[i]);
        float od = (float)out_cnt[i];
        float ns = 1.0f / sqrtf(fmaxf(od, 1.0f));
        norm_s[i] = ns;
        norm_d[i] = 1.0f / sqrtf(fmaxf(id, 1.0f));
        h0s[i * 3 + 0] = id * ns;
        h0s[i * 3 + 1] = cx[i] * ns;
        h0s[i * 3 + 2] = cy[i] * ns;
    }
}

// ---------------- W2..W5 -> bf16, transposed: Wt[l][n][k] = bf16(W[k][n]) ----------------
__global__ __launch_bounds__(256) void convw_kernel(const float* __restrict__ W2,
                                                    const float* __restrict__ W3,
                                                    const float* __restrict__ W4,
                                                    const float* __restrict__ W5,
                                                    unsigned short* __restrict__ Wt) {
    int gid = blockIdx.x * 256 + threadIdx.x;
    if (gid < 4 * 16384) {
        int l = gid >> 14, idx = gid & 16383;
        int n = idx >> 7, k = idx & 127;
        const float* W = (l == 0) ? W2 : (l == 1) ? W3 : (l == 2) ? W4 : W5;
        Wt[gid] = f2bf(W[k * 128 + n]);
    }
}

// ---------------- layer-1 gather (F=3), compact CSR ----------------
__global__ __launch_bounds__(256) void gather3_kernel(const int* __restrict__ row_ptr,
                                                      const int* __restrict__ col,
                                                      const float* __restrict__ h0s,
                                                      const float* __restrict__ norm_d,
                                                      float* __restrict__ agg3) {
    int n = blockIdx.x * 256 + threadIdx.x;
    if (n < NN) {
        float a0 = 0.f, a1 = 0.f, a2 = 0.f;
        int end = row_ptr[n + 1];
        for (int e = row_ptr[n]; e < end; ++e) {
            int s = col[e];
            a0 += h0s[s * 3 + 0];
            a1 += h0s[s * 3 + 1];
            a2 += h0s[s * 3 + 2];
        }
        float nd = norm_d[n];
        agg3[n * 3 + 0] = a0 * nd;
        agg3[n * 3 + 1] = a1 * nd;
        agg3[n * 3 + 2] = a2 * nd;
    }
}

// ---------------- layer-1 node (3 -> 128), bf16 out pre-scaled by norm_s ----------------
__global__ __launch_bounds__(256) void node3_kernel(const float* __restrict__ agg3,
                                                    const float* __restrict__ norm_s,
                                                    const float* __restrict__ W1,
                                                    const float* __restrict__ b1,
                                                    unsigned short* __restrict__ h1s) {
    int gid = blockIdx.x * 256 + threadIdx.x;
    int i = gid >> 7, c = gid & 127;
    if (i < NN) {
        float a0 = agg3[i * 3 + 0];
        float a1 = agg3[i * 3 + 1];
        float a2 = agg3[i * 3 + 2];
        float v = a0 * W1[c] + a1 * W1[128 + c] + a2 * W1[256 + c] + b1[c];
        h1s[i * 128 + c] = f2bf(fmaxf(v, 0.0f) * norm_s[i]);
    }
}

// ---------------- edge aggregation F=128: bf16 gather, compact CSR ----------------
// One WAVE per node (wave-uniform edge loop). Lane owns 2 features (1 dword).
__global__ __launch_bounds__(256) void gather_bf16_kernel(const int* __restrict__ row_ptr,
                                                          const int* __restrict__ col,
                                                          const unsigned int* __restrict__ hs2,
                                                          const float* __restrict__ norm_d,
                                                          unsigned int* __restrict__ aggb2) {
    int t = threadIdx.x;
    int wave = t >> 6;
    int lane = t & 63;
    int n = blockIdx.x * 4 + wave;
    if (n >= NN) return;
    int beg = row_ptr[n], end = row_ptr[n + 1];
    const unsigned int* hb = hs2 + lane;
    float ax = 0.f, ay = 0.f;
    int e = beg;
    for (; e + 7 < end; e += 8) {
        unsigned u[8];
        #pragma unroll
        for (int j = 0; j < 8; ++j) u[j] = hb[(long)col[e + j] << 6];
        #pragma unroll
        for (int j = 0; j < 8; ++j) {
            ax += __uint_as_float(u[j] << 16);
            ay += __uint_as_float(u[j] & 0xffff0000u);
        }
    }
    for (; e < end; ++e) {
        unsigned u0 = hb[(long)col[e] << 6];
        ax += __uint_as_float(u0 << 16);
        ay += __uint_as_float(u0 & 0xffff0000u);
    }
    float nd = norm_d[n];
    unsigned po = (unsigned)f2bf(ax * nd) | ((unsigned)f2bf(ay * nd) << 16);
    aggb2[(n << 6) + lane] = po;
}

// ---------------- node GEMM via MFMA bf16: relu(aggb @ W + b) ----------------
// D mapping (m89-verified): col = lane&15, row = (lane>>4)*4 + reg.
__global__ __launch_bounds__(256) void gemm_mfma_kernel(const unsigned short* __restrict__ aggb,
                                                        const float* __restrict__ scale,
                                                        const unsigned short* __restrict__ Wt,
                                                        const float* __restrict__ bias,
                                                        unsigned short* __restrict__ out_bf,
                                                        float* __restrict__ out_f32,
                                                        float* __restrict__ embsum) {
    __shared__ unsigned short ldsw[128][136];
    __shared__ float ldscol[4][4][128];

    int t = threadIdx.x;
    int wv = t >> 6, lane = t & 63;
    int fr = lane & 15, kq = lane >> 4;
    int m0 = blockIdx.x * 64 + wv * 16;

    // stage Wt (32 KB) into LDS, coalesced 16B per lane
    #pragma unroll
    for (int i = 0; i < 8; ++i) {
        int idx = t + 256 * i;
        int r = idx >> 4;
        int c8 = (idx & 15) << 3;
        *(bf16x8v*)(&ldsw[r][c8]) = *(const bf16x8v*)(Wt + (r << 7) + c8);
    }

    int mrow = m0 + fr;
    long abase = (long)((mrow < NN) ? mrow : 0) << 7;
    bf16x8v a0 = *(const bf16x8v*)(aggb + abase + 0  + kq * 8);
    bf16x8v a1 = *(const bf16x8v*)(aggb + abase + 32 + kq * 8);
    bf16x8v a2 = *(const bf16x8v*)(aggb + abase + 64 + kq * 8);
    bf16x8v a3 = *(const bf16x8v*)(aggb + abase + 96 + kq * 8);

    float sc[4];
    #pragma unroll
    for (int r = 0; r < 4; ++r) {
        int mr = m0 + kq * 4 + r;
        sc[r] = (out_bf && mr < NN) ? scale[mr] : 1.0f;
    }

    __syncthreads();

    #pragma unroll
    for (int nt = 0; nt < 8; ++nt) {
        int n0 = nt << 4;
        f32x4v acc = {0.f, 0.f, 0.f, 0.f};
        acc = __builtin_amdgcn_mfma_f32_16x16x32_bf16(a0, *(const bf16x8v*)(&ldsw[n0 + fr][0  + kq * 8]), acc, 0, 0, 0);
        acc = __builtin_amdgcn_mfma_f32_16x16x32_bf16(a1, *(const bf16x8v*)(&ldsw[n0 + fr][32 + kq * 8]), acc, 0, 0, 0);
        acc = __builtin_amdgcn_mfma_f32_16x16x32_bf16(a2, *(const bf16x8v*)(&ldsw[n0 + fr][64 + kq * 8]), acc, 0, 0, 0);
        acc = __builtin_amdgcn_mfma_f32_16x16x32_bf16(a3, *(const bf16x8v*)(&ldsw[n0 + fr][96 + kq * 8]), acc, 0, 0, 0);

        float bv = bias[n0 + fr];
        float cs = 0.f;
        #pragma unroll
        for (int r = 0; r < 4; ++r) {
            int mr = m0 + kq * 4 + r;
            if (mr < NN) {
                float v = fmaxf(acc[r] + bv, 0.f);
                if (out_bf) out_bf[((long)mr << 7) + n0 + fr] = f2bf(v * sc[r]);
                else        out_f32[((long)mr << 7) + n0 + fr] = v;
                cs += v;
            }
        }
        if (embsum) ldscol[wv][kq][n0 + fr] = cs;
    }

    if (embsum) {
        __syncthreads();
        if (t < 128) {
            float s = 0.f;
            #pragma unroll
            for (int w = 0; w < 4; ++w)
                #pragma unroll
                for (int q = 0; q < 4; ++q)
                    s += ldscol[w][q][t];
            atomicAdd(&embsum[t], s);
        }
    }
}

// ---------------- head MLP ----------------
__global__ __launch_bounds__(128) void head_kernel(const float* __restrict__ embsum,
                                                   const float* __restrict__ Wl1,
                                                   const float* __restrict__ bl1,
                                                   const float* __restrict__ Wl2,
                                                   const float* __restrict__ bl2,
                                                   float* __restrict__ d_out) {
    __shared__ float emb[128];
    __shared__ float hemb[64];
    int t = threadIdx.x;
    float e = embsum[t] * (1.0f / (float)NN);
    emb[t] = e;
    d_out[1 + t] = e;
    __syncthreads();
    if (t < 64) {
        float acc = bl1[t];
        for (int k = 0; k < 128; ++k)
            acc += emb[k] * Wl1[k * 64 + t];
        hemb[t] = fmaxf(acc, 0.f);
    }
    __syncthreads();
    if (t == 0) {
        float acc = bl2[0];
        for (int j = 0; j < 64; ++j)
            acc += hemb[j] * Wl2[j];
        d_out[0] = 1.0f / (1.0f + expf(-acc));
    }
}

extern "C" void kernel_launch(void* const* d_in, const int* in_sizes, int n_in,
                              void* d_out, int out_size, void* d_ws, size_t ws_size,
                              hipStream_t stream) {
    const float* cx  = (const float*)d_in[0];
    const float* cy  = (const float*)d_in[1];
    const float* W1  = (const float*)d_in[2];
    const float* b1  = (const float*)d_in[3];
    const float* W2  = (const float*)d_in[4];
    const float* b2  = (const float*)d_in[5];
    const float* W3  = (const float*)d_in[6];
    const float* b3  = (const float*)d_in[7];
    const float* W4  = (const float*)d_in[8];
    const float* b4  = (const float*)d_in[9];
    const float* W5  = (const float*)d_in[10];
    const float* b5  = (const float*)d_in[11];
    const float* Wl1 = (const float*)d_in[12];
    const float* bl1 = (const float*)d_in[13];
    const float* Wl2 = (const float*)d_in[14];
    const float* bl2 = (const float*)d_in[15];
    const int*   src = (const int*)d_in[16];
    const int*   dst = (const int*)d_in[17];

    float* out = (float*)d_out;
    float* h_out = out + 129;

    // workspace layout (float-index units)
    float* ws       = (float*)d_ws;
    float* norm_s   = ws;                                   // N
    float* norm_d   = ws + NN;                              // N
    int*   out_cnt  = (int*)(ws + 2 * NN);                  // N
    int*   row_ptr  = (int*)(ws + 3 * NN);                  // N+1
    unsigned short* hs   = (unsigned short*)(ws + 4 * NN + 64);   // 128N bf16
    unsigned short* aggb = (unsigned short*)(ws + 68 * NN + 64);  // 128N bf16
    int*   col      = (int*)(ws + 132 * NN + 64);           // NE
    float* h0s      = ws + 148 * NN + 64;                   // 3N
    float* agg3     = ws + 151 * NN + 64;                   // 3N
    unsigned short* Wt = (unsigned short*)(ws + 154 * NN + 64);   // 4*16384 bf16
    float* embsum   = ws + 154 * NN + 64 + 32768;           // 128
    int*   dcur     = (int*)(ws + 154 * NN + 33600);        // NB
    int*   scur     = dcur + NB;                            // NB
    int2*  dbucket  = (int2*)(ws + 154 * NN + 34048);       // NB*CAP int2
    int*   sbucket  = (int*)(ws + 154 * NN + 34048 + 2 * NB * CAP);  // NB*CAP int

    // 1. two-level bucket CSR build (atomic-light)
    hipMemsetAsync(dcur, 0, 2 * NB * sizeof(int), stream);
    bucket_kernel<<<(NE + B1_EPB - 1) / B1_EPB, 256, 0, stream>>>(src, dst, dcur, scur,
                                                                  dbucket, sbucket);
    csr_dst_kernel<<<NB, 256, 0, stream>>>(dbucket, dcur, row_ptr, col);
    outdeg_kernel<<<NB, 256, 0, stream>>>(sbucket, scur, out_cnt);

    // 2. norms + scaled h0; weight convert (independent)
    node_init_kernel<<<(NN + 255) / 256, 256, 0, stream>>>(cx, cy, row_ptr, out_cnt,
                                                           norm_s, norm_d, h0s);
    convw_kernel<<<256, 256, 0, stream>>>(W2, W3, W4, W5, Wt);

    // 3. layer 1 (F_in = 3)
    gather3_kernel<<<(NN + 255) / 256, 256, 0, stream>>>(row_ptr, col, h0s, norm_d, agg3);
    node3_kernel<<<(NN * 128) / 256, 256, 0, stream>>>(agg3, norm_s, W1, b1, hs);

    // 4. layers 2..5: bf16 gather + MFMA GEMM (+ fused colsum on last)
    hipMemsetAsync(embsum, 0, 128 * sizeof(float), stream);
    const float* bs[4] = {b2, b3, b4, b5};
    const int gather_blocks = (NN + 3) / 4;
    const int gemm_blocks = (NN + 63) / 64;
    for (int l = 0; l < 4; ++l) {
        gather_bf16_kernel<<<gather_blocks, 256, 0, stream>>>(row_ptr, col,
                                                              (const unsigned int*)hs,
                                                              norm_d,
                                                              (unsigned int*)aggb);
        bool last = (l == 3);
        gemm_mfma_kernel<<<gemm_blocks, 256, 0, stream>>>(
            aggb, norm_s, Wt + l * 16384, bs[l],
            last ? nullptr : hs,
            last ? h_out : nullptr,
            last ? embsum : nullptr);
    }

    // 5. head
    head_kernel<<<1, 128, 0, stream>>>(embsum, Wl1, bl1, Wl2, bl2, out);
}